// Round 1
// baseline (27590.262 us; speedup 1.0000x reference)
//
#include <hip/hip_runtime.h>
#include <hip/hip_bf16.h>
#include <math.h>

// ViT config
#define VB   32
#define VS   197
#define VD   768
#define VNH  12
#define VDQ  64
#define VL   12
#define VMLP 3072
#define VC   1000
#define VP   256
#define VNPAT 196
#define VTOK (VB * VS)            // 6304
#define TOKD ((size_t)VTOK * VD)  // 4841472 floats

// ---------------------------------------------------------------------------
// patchify: X (B,224,224) -> patches (B,196,256)
// ---------------------------------------------------------------------------
__global__ void patchify_k(const float* __restrict__ X, float* __restrict__ P) {
    int idx = blockIdx.x * 256 + threadIdx.x;
    const int total = VB * VNPAT * VP;
    if (idx >= total) return;
    int i  = idx & 255;
    int p  = (idx >> 8) % VNPAT;
    int b  = (idx >> 8) / VNPAT;
    int pr = p / 14, pc = p % 14;
    int a  = i >> 4, c2 = i & 15;
    P[idx] = X[((size_t)b * 224 + pr * 16 + a) * 224 + pc * 16 + c2];
}

// ---------------------------------------------------------------------------
// cls token + sinusoidal positional embeddings
// ---------------------------------------------------------------------------
__global__ void pos_cls_k(float* __restrict__ x, const float* __restrict__ cls) {
    size_t idx = (size_t)blockIdx.x * 256 + threadIdx.x;
    if (idx >= TOKD) return;
    int j = (int)(idx % VD);
    int s = (int)((idx / VD) % VS);
    float jj = (float)(j & ~1);
    // 10000^{-jj/768} = exp(-(jj/768)*ln(10000))
    float freq = expf(-(jj / (float)VD) * 9.2103403719761836f);
    float ang  = (float)s * freq;
    float pe   = (j & 1) ? cosf(ang) : sinf(ang);
    if (s == 0) x[idx] = cls[j] + pe;
    else        x[idx] += pe;
}

// ---------------------------------------------------------------------------
// LayerNorm: one block per token, 256 threads, 3 elems/thread
// ---------------------------------------------------------------------------
__global__ __launch_bounds__(256) void layernorm_k(
    const float* __restrict__ x, float* __restrict__ y,
    const float* __restrict__ g, const float* __restrict__ bta)
{
    int t = blockIdx.x;
    const float* xr = x + (size_t)t * VD;
    float*       yr = y + (size_t)t * VD;
    int tid = threadIdx.x;
    float v[3];
    float s = 0.f;
    #pragma unroll
    for (int i = 0; i < 3; i++) { v[i] = xr[tid + i * 256]; s += v[i]; }
    __shared__ float red[8];
    #pragma unroll
    for (int off = 32; off; off >>= 1) s += __shfl_xor(s, off);
    int lane = tid & 63, w = tid >> 6;
    if (!lane) red[w] = s;
    __syncthreads();
    float mu = (red[0] + red[1] + red[2] + red[3]) * (1.f / VD);
    float s2 = 0.f;
    #pragma unroll
    for (int i = 0; i < 3; i++) { float d0 = v[i] - mu; s2 += d0 * d0; }
    #pragma unroll
    for (int off = 32; off; off >>= 1) s2 += __shfl_xor(s2, off);
    if (!lane) red[4 + w] = s2;
    __syncthreads();
    float var = (red[4] + red[5] + red[6] + red[7]) * (1.f / VD);
    float rs = rsqrtf(var + 1e-5f);
    #pragma unroll
    for (int i = 0; i < 3; i++) {
        int j = tid + i * 256;
        yr[j] = (v[i] - mu) * rs * g[j] + bta[j];
    }
}

// ---------------------------------------------------------------------------
// Generic tiled SGEMM: C[M,N] (+)= A[M,K] @ B[K,N] + bias
// BM=BN=64, BK=16, 256 threads, 4x4 per thread.
// ROWMAP=1: patch-embed row remap (A row r -> x row r + r/196 + 1)
// GELU=1: exact gelu epilogue.  ACC=1: accumulate into C (residual).
// K must be a multiple of 16.
// ---------------------------------------------------------------------------
template<int ACC, int GELU, int ROWMAP>
__global__ __launch_bounds__(256) void gemm_k(
    const float* __restrict__ A, int lda,
    const float* __restrict__ Bw, int ldb,
    const float* __restrict__ bias,
    float* __restrict__ Cm, int ldc,
    int M, int N, int K)
{
    __shared__ float As[16][68];
    __shared__ float Bs[16][68];
    const int tid = threadIdx.x;
    const int tr = tid >> 4, tc = tid & 15;
    const int row0 = blockIdx.y * 64, col0 = blockIdx.x * 64;
    float acc[4][4] = {{0.f}};
    const int nk = K >> 4;
    for (int kt = 0; kt < nk; kt++) {
        const int k0 = kt << 4;
        #pragma unroll
        for (int i = 0; i < 4; i++) {
            int idx = tid + i * 256;
            int r = idx >> 4, c = idx & 15;
            int gr = row0 + r;
            As[c][r] = (gr < M) ? A[(size_t)gr * lda + (k0 + c)] : 0.f;
        }
        #pragma unroll
        for (int i = 0; i < 4; i++) {
            int idx = tid + i * 256;
            int rr = idx >> 6, cc = idx & 63;
            int gc = col0 + cc;
            Bs[rr][cc] = (gc < N) ? Bw[(size_t)(k0 + rr) * ldb + gc] : 0.f;
        }
        __syncthreads();
        #pragma unroll
        for (int kk = 0; kk < 16; kk++) {
            float4 av  = *(const float4*)&As[kk][tr * 4];
            float4 bv4 = *(const float4*)&Bs[kk][tc * 4];
            float a4[4] = {av.x, av.y, av.z, av.w};
            float b4[4] = {bv4.x, bv4.y, bv4.z, bv4.w};
            #pragma unroll
            for (int i = 0; i < 4; i++)
                #pragma unroll
                for (int j = 0; j < 4; j++)
                    acc[i][j] = fmaf(a4[i], b4[j], acc[i][j]);
        }
        __syncthreads();
    }
    #pragma unroll
    for (int i = 0; i < 4; i++) {
        int r = row0 + tr * 4 + i;
        if (r >= M) continue;
        size_t crow = ROWMAP ? (size_t)(r + r / VNPAT + 1) : (size_t)r;
        #pragma unroll
        for (int j = 0; j < 4; j++) {
            int c = col0 + tc * 4 + j;
            if (c >= N) continue;
            float v = acc[i][j] + bias[c];
            if (GELU) v = 0.5f * v * (1.f + erff(v * 0.70710678118654752f));
            if (ACC) Cm[crow * ldc + c] += v;
            else     Cm[crow * ldc + c] = v;
        }
    }
}

// ---------------------------------------------------------------------------
// Fused QKV GEMM: n1 (B,S,D) x W{q,k,v}[l] (NH,D,DQ) -> q/k/v (B*NH, S, DQ)
// grid: (ceil(S/64), 3*B*NH)
// ---------------------------------------------------------------------------
__global__ __launch_bounds__(256) void qkv_gemm_k(
    const float* __restrict__ n1,
    const float* __restrict__ Wq, const float* __restrict__ Wk, const float* __restrict__ Wv,
    const float* __restrict__ bq, const float* __restrict__ bk, const float* __restrict__ bv,
    float* __restrict__ qo, float* __restrict__ ko, float* __restrict__ vo)
{
    __shared__ float As[16][68];
    __shared__ float Bs[16][68];
    const int tid = threadIdx.x;
    const int tr = tid >> 4, tc = tid & 15;
    const int zz = blockIdx.y;
    const int m  = zz / (VB * VNH);
    const int bh = zz % (VB * VNH);
    const int b  = bh / VNH, h = bh % VNH;
    const int row0 = blockIdx.x * 64;
    const float* A    = n1 + (size_t)b * VS * VD;
    const float* W    = (m == 0 ? Wq : m == 1 ? Wk : Wv) + (size_t)h * VD * VDQ;
    const float* bias = (m == 0 ? bq : m == 1 ? bk : bv) + h * VDQ;
    float* out = (m == 0 ? qo : m == 1 ? ko : vo) + (size_t)bh * VS * VDQ;
    float acc[4][4] = {{0.f}};
    for (int k0 = 0; k0 < VD; k0 += 16) {
        #pragma unroll
        for (int i = 0; i < 4; i++) {
            int idx = tid + i * 256;
            int r = idx >> 4, c = idx & 15;
            int gr = row0 + r;
            As[c][r] = (gr < VS) ? A[(size_t)gr * VD + (k0 + c)] : 0.f;
        }
        #pragma unroll
        for (int i = 0; i < 4; i++) {
            int idx = tid + i * 256;
            int rr = idx >> 6, cc = idx & 63;
            Bs[rr][cc] = W[(size_t)(k0 + rr) * VDQ + cc];
        }
        __syncthreads();
        #pragma unroll
        for (int kk = 0; kk < 16; kk++) {
            float4 av  = *(const float4*)&As[kk][tr * 4];
            float4 bv4 = *(const float4*)&Bs[kk][tc * 4];
            float a4[4] = {av.x, av.y, av.z, av.w};
            float b4[4] = {bv4.x, bv4.y, bv4.z, bv4.w};
            #pragma unroll
            for (int i = 0; i < 4; i++)
                #pragma unroll
                for (int j = 0; j < 4; j++)
                    acc[i][j] = fmaf(a4[i], b4[j], acc[i][j]);
        }
        __syncthreads();
    }
    #pragma unroll
    for (int i = 0; i < 4; i++) {
        int r = row0 + tr * 4 + i;
        if (r >= VS) continue;
        #pragma unroll
        for (int j = 0; j < 4; j++) {
            int c = tc * 4 + j;
            out[(size_t)r * VDQ + c] = acc[i][j] + bias[c];
        }
    }
}

// ---------------------------------------------------------------------------
// Attention: per (b,h), 8 query rows per block, 512 threads (8 waves).
// q,k,v in (B*NH, S, DQ). Writes o into (B, S, D) layout (head-concat).
// ---------------------------------------------------------------------------
#define AROWS 8
__global__ __launch_bounds__(512) void attn_k(
    const float* __restrict__ q, const float* __restrict__ k,
    const float* __restrict__ v, float* __restrict__ o, float scale)
{
    const int bh = blockIdx.y;
    const int r0 = blockIdx.x * AROWS;
    const int b = bh / VNH, h = bh % VNH;
    const float* qb = q + (size_t)bh * VS * VDQ;
    const float* kb = k + (size_t)bh * VS * VDQ;
    const float* vb = v + (size_t)bh * VS * VDQ;
    __shared__ float q_s[AROWS][VDQ + 1];
    __shared__ float t_s[64][VDQ + 1];
    __shared__ float sc[AROWS][256];
    const int tid = threadIdx.x;
    const int r = tid >> 6, tl = tid & 63;   // wave index = row, lane = col
    for (int idx = tid; idx < AROWS * VDQ; idx += 512) {
        int rr = idx / VDQ, d = idx % VDQ;
        q_s[rr][d] = (r0 + rr < VS) ? qb[(size_t)(r0 + rr) * VDQ + d] : 0.f;
    }
    // scores
    for (int t0 = 0; t0 < VS; t0 += 64) {
        __syncthreads();
        for (int idx = tid; idx < 64 * VDQ; idx += 512) {
            int tt = idx / VDQ, d = idx % VDQ;
            t_s[tt][d] = (t0 + tt < VS) ? kb[(size_t)(t0 + tt) * VDQ + d] : 0.f;
        }
        __syncthreads();
        int t = t0 + tl;
        float acc = 0.f;
        #pragma unroll
        for (int d = 0; d < VDQ; d++) acc = fmaf(q_s[r][d], t_s[tl][d], acc);
        if (t < VS) sc[r][t] = acc * scale;
    }
    // softmax: wave r owns row r (no cross-wave deps on sc[r][*])
    {
        float m = -INFINITY;
        for (int t = tl; t < VS; t += 64) m = fmaxf(m, sc[r][t]);
        #pragma unroll
        for (int off = 32; off; off >>= 1) m = fmaxf(m, __shfl_xor(m, off));
        float sum = 0.f;
        for (int t = tl; t < VS; t += 64) {
            float p = expf(sc[r][t] - m);
            sc[r][t] = p;
            sum += p;
        }
        #pragma unroll
        for (int off = 32; off; off >>= 1) sum += __shfl_xor(sum, off);
        float inv = 1.f / sum;
        for (int t = tl; t < VS; t += 64) sc[r][t] *= inv;
    }
    // o = att @ v : thread (r, e=tl)
    float acc = 0.f;
    for (int t0 = 0; t0 < VS; t0 += 64) {
        __syncthreads();
        for (int idx = tid; idx < 64 * VDQ; idx += 512) {
            int tt = idx / VDQ, d = idx % VDQ;
            t_s[tt][d] = (t0 + tt < VS) ? vb[(size_t)(t0 + tt) * VDQ + d] : 0.f;
        }
        __syncthreads();
        int tmax = min(64, VS - t0);
        for (int tt = 0; tt < tmax; tt++)
            acc = fmaf(sc[r][t0 + tt], t_s[tt][tl], acc);
    }
    if (r0 + r < VS)
        o[((size_t)b * VS + r0 + r) * VD + h * VDQ + tl] = acc;
}

// ---------------------------------------------------------------------------
extern "C" void kernel_launch(void* const* d_in, const int* in_sizes, int n_in,
                              void* d_out, int out_size, void* d_ws, size_t ws_size,
                              hipStream_t stream) {
    (void)in_sizes; (void)n_in; (void)out_size; (void)ws_size;
    const float* X       = (const float*)d_in[0];
    const float* patch_W = (const float*)d_in[1];
    const float* patch_b = (const float*)d_in[2];
    const float* cls_tok = (const float*)d_in[3];
    const float* ln1_g   = (const float*)d_in[4];
    const float* ln1_b   = (const float*)d_in[5];
    const float* Wq      = (const float*)d_in[6];
    const float* bq      = (const float*)d_in[7];
    const float* Wk      = (const float*)d_in[8];
    const float* bk      = (const float*)d_in[9];
    const float* Wv      = (const float*)d_in[10];
    const float* bv      = (const float*)d_in[11];
    const float* proj_W  = (const float*)d_in[12];
    const float* proj_b  = (const float*)d_in[13];
    const float* ln2_g   = (const float*)d_in[14];
    const float* ln2_b   = (const float*)d_in[15];
    const float* mlp_W1  = (const float*)d_in[16];
    const float* mlp_b1  = (const float*)d_in[17];
    const float* mlp_W2  = (const float*)d_in[18];
    const float* mlp_b2  = (const float*)d_in[19];
    const float* head_W  = (const float*)d_in[20];
    const float* head_b  = (const float*)d_in[21];

    float* ws   = (float*)d_ws;
    float* x    = ws;             // (B,S,D)
    float* n    = ws + TOKD;      // LN out / attention out
    float* qb   = ws + 2 * TOKD;  // (B*NH, S, DQ)
    float* kb   = ws + 3 * TOKD;
    float* vb   = ws + 4 * TOKD;
    float* hbuf = qb;             // MLP hidden chunk (3152 x 3072) reuses q+k

    // 1. patchify into q buffer region
    {
        int total = VB * VNPAT * VP;
        patchify_k<<<(total + 255) / 256, 256, 0, stream>>>(X, qb);
    }
    // 2. patch embed: (6272 x 256) @ (256 x 768), remapped into x rows
    {
        dim3 g((VD + 63) / 64, (VB * VNPAT + 63) / 64);
        gemm_k<0, 0, 1><<<g, 256, 0, stream>>>(qb, VP, patch_W, VD, patch_b,
                                               x, VD, VB * VNPAT, VD, VP);
    }
    // 3. cls + positional embeddings
    {
        size_t total = TOKD;
        pos_cls_k<<<(unsigned)((total + 255) / 256), 256, 0, stream>>>(x, cls_tok);
    }

    const float scale = 0.125f;  // 1/sqrt(64)
    for (int l = 0; l < VL; l++) {
        layernorm_k<<<VTOK, 256, 0, stream>>>(x, n, ln1_g + l * VD, ln1_b + l * VD);

        dim3 gq((VS + 63) / 64, 3 * VB * VNH);
        qkv_gemm_k<<<gq, 256, 0, stream>>>(n,
            Wq + (size_t)l * VNH * VD * VDQ, Wk + (size_t)l * VNH * VD * VDQ,
            Wv + (size_t)l * VNH * VD * VDQ,
            bq + l * VNH * VDQ, bk + l * VNH * VDQ, bv + l * VNH * VDQ,
            qb, kb, vb);

        dim3 ga((VS + AROWS - 1) / AROWS, VB * VNH);
        attn_k<<<ga, 512, 0, stream>>>(qb, kb, vb, n, scale);

        dim3 gp((VD + 63) / 64, (VTOK + 63) / 64);
        gemm_k<1, 0, 0><<<gp, 256, 0, stream>>>(n, VD,
            proj_W + (size_t)l * VD * VD, VD, proj_b + l * VD,
            x, VD, VTOK, VD, VD);

        layernorm_k<<<VTOK, 256, 0, stream>>>(x, n, ln2_g + l * VD, ln2_b + l * VD);

        // MLP in 2 token chunks (hidden reuses q+k buffers)
        const int CH = VTOK / 2; // 3152
        for (int c = 0; c < 2; c++) {
            int m0 = c * CH;
            dim3 g1((VMLP + 63) / 64, (CH + 63) / 64);
            gemm_k<0, 1, 0><<<g1, 256, 0, stream>>>(n + (size_t)m0 * VD, VD,
                mlp_W1 + (size_t)l * VD * VMLP, VMLP, mlp_b1 + l * VMLP,
                hbuf, VMLP, CH, VMLP, VD);
            dim3 g2((VD + 63) / 64, (CH + 63) / 64);
            gemm_k<1, 0, 0><<<g2, 256, 0, stream>>>(hbuf, VMLP,
                mlp_W2 + (size_t)l * VMLP * VD, VD, mlp_b2 + l * VD,
                x + (size_t)m0 * VD, VD, CH, VD, VMLP);
        }
    }
    // head: x[:,0] (32 x 768) @ (768 x 1000)
    {
        dim3 gh((VC + 63) / 64, 1);
        gemm_k<0, 0, 0><<<gh, 256, 0, stream>>>(x, VS * VD, head_W, VC, head_b,
                                                (float*)d_out, VC, VB, VC, VD);
    }
}

// Round 2
// 6461.313 us; speedup vs baseline: 4.2701x; 4.2701x over previous
//
#include <hip/hip_runtime.h>
#include <hip/hip_bf16.h>
#include <math.h>
#include <stdint.h>

// ViT config
#define VB   32
#define VS   197
#define VD   768
#define VNH  12
#define VDQ  64
#define VL   12
#define VMLP 3072
#define VC   1000
#define VP   256
#define VNPAT 196
#define VTOK (VB * VS)            // 6304
#define TOKD ((size_t)VTOK * VD)  // 4841472 floats

typedef __attribute__((ext_vector_type(4))) float f32x4;
typedef __attribute__((ext_vector_type(8))) short short8;

typedef __attribute__((address_space(1))) const unsigned int GU;
typedef __attribute__((address_space(3))) unsigned int LU;

__device__ __forceinline__ void gload_lds16(const void* g, void* l) {
    __builtin_amdgcn_global_load_lds((GU*)(uintptr_t)g, (LU*)(uintptr_t)l, 16, 0, 0);
}

// ---------------------------------------------------------------------------
// patchify: X (B,224,224) fp32 -> patches (B*196, 256) bf16
// ---------------------------------------------------------------------------
__global__ void patchify_k(const float* __restrict__ X, __hip_bfloat16* __restrict__ P) {
    int idx = blockIdx.x * 256 + threadIdx.x;
    const int total = VB * VNPAT * VP;
    if (idx >= total) return;
    int i  = idx & 255;
    int p  = (idx >> 8) % VNPAT;
    int b  = (idx >> 8) / VNPAT;
    int pr = p / 14, pc = p % 14;
    int a  = i >> 4, c2 = i & 15;
    P[idx] = __float2bfloat16(X[((size_t)b * 224 + pr * 16 + a) * 224 + pc * 16 + c2]);
}

// ---------------------------------------------------------------------------
// cls token + sinusoidal positional embeddings (x fp32)
// ---------------------------------------------------------------------------
__global__ void pos_cls_k(float* __restrict__ x, const float* __restrict__ cls) {
    size_t idx = (size_t)blockIdx.x * 256 + threadIdx.x;
    if (idx >= TOKD) return;
    int j = (int)(idx % VD);
    int s = (int)((idx / VD) % VS);
    float jj = (float)(j & ~1);
    float freq = expf(-(jj / (float)VD) * 9.2103403719761836f);
    float ang  = (float)s * freq;
    float pe   = (j & 1) ? cosf(ang) : sinf(ang);
    if (s == 0) x[idx] = cls[j] + pe;
    else        x[idx] += pe;
}

// ---------------------------------------------------------------------------
// LayerNorm: x fp32 -> y bf16. One block per token.
// ---------------------------------------------------------------------------
__global__ __launch_bounds__(256) void layernorm_k(
    const float* __restrict__ x, __hip_bfloat16* __restrict__ y,
    const float* __restrict__ g, const float* __restrict__ bta)
{
    int t = blockIdx.x;
    const float* xr = x + (size_t)t * VD;
    __hip_bfloat16* yr = y + (size_t)t * VD;
    int tid = threadIdx.x;
    float v[3];
    float s = 0.f;
    #pragma unroll
    for (int i = 0; i < 3; i++) { v[i] = xr[tid + i * 256]; s += v[i]; }
    __shared__ float red[8];
    #pragma unroll
    for (int off = 32; off; off >>= 1) s += __shfl_xor(s, off);
    int lane = tid & 63, w = tid >> 6;
    if (!lane) red[w] = s;
    __syncthreads();
    float mu = (red[0] + red[1] + red[2] + red[3]) * (1.f / VD);
    float s2 = 0.f;
    #pragma unroll
    for (int i = 0; i < 3; i++) { float d0 = v[i] - mu; s2 += d0 * d0; }
    #pragma unroll
    for (int off = 32; off; off >>= 1) s2 += __shfl_xor(s2, off);
    if (!lane) red[4 + w] = s2;
    __syncthreads();
    float var = (red[4] + red[5] + red[6] + red[7]) * (1.f / VD);
    float rs = rsqrtf(var + 1e-5f);
    #pragma unroll
    for (int i = 0; i < 3; i++) {
        int j = tid + i * 256;
        yr[j] = __float2bfloat16((v[i] - mu) * rs * g[j] + bta[j]);
    }
}

// ---------------------------------------------------------------------------
// Batched transpose + bf16 convert: in (G,R,C) fp32 -> out (G,C,R) bf16.
// R, C multiples of 32. grid (C/32, R/32, G), 256 threads.
// ---------------------------------------------------------------------------
__global__ __launch_bounds__(256) void tpose_k(
    const float* __restrict__ in, __hip_bfloat16* __restrict__ out, int R, int C)
{
    __shared__ float t[32][33];
    const float* ing = in + (size_t)blockIdx.z * R * C;
    __hip_bfloat16* outg = out + (size_t)blockIdx.z * R * C;
    int c0 = blockIdx.x * 32, r0 = blockIdx.y * 32;
    int tc = threadIdx.x & 31, tr = threadIdx.x >> 5;
    #pragma unroll
    for (int p = 0; p < 4; p++)
        t[tr + p * 8][tc] = ing[(size_t)(r0 + tr + p * 8) * C + c0 + tc];
    __syncthreads();
    #pragma unroll
    for (int p = 0; p < 4; p++)
        outg[(size_t)(c0 + tr + p * 8) * R + r0 + tc] = __float2bfloat16(t[tc][tr + p * 8]);
}

// combined qkv bias: cb[n], n in [0,2304)
__global__ void cbias_k(const float* __restrict__ bq, const float* __restrict__ bk,
                        const float* __restrict__ bv, float* __restrict__ cb) {
    int n = blockIdx.x * 256 + threadIdx.x;
    if (n >= 3 * VD) return;
    int m = n / VD, wi = n % VD;
    const float* p = (m == 0) ? bq : (m == 1) ? bk : bv;
    cb[n] = p[wi];
}

// ---------------------------------------------------------------------------
// bf16 MFMA GEMM: C[M,N] = A[M,K](bf16) @ BT[N,K](bf16)^T + bias
// BM=BN=128, BK=64 elems, 256 threads (4 waves, 2x2), 4x4 16x16x32 frags/wave.
// XOR slot swizzle (slot ^= row&7) applied on the global->LDS source AND the
// ds_read side -> conflict-free ds_read_b128.
// EPI: 0 = fp32 store with patch rowmap; 1 = bf16 store; 2 = fp32 accumulate;
//      3 = exact-GELU -> bf16 store.   N multiple of 128; M clamped.
// ---------------------------------------------------------------------------
template<int EPI>
__global__ __launch_bounds__(256) void bgemm_k(
    const __hip_bfloat16* __restrict__ A,
    const __hip_bfloat16* __restrict__ BT,
    const float* __restrict__ bias,
    void* __restrict__ Co,
    int M, int K, int ldc)
{
    __shared__ short A_s[128][64];
    __shared__ short B_s[128][64];
    const int tid = threadIdx.x;
    const int w = tid >> 6, l = tid & 63;
    const int row0 = blockIdx.y * 128, col0 = blockIdx.x * 128;
    const int wm = (w >> 1) << 6, wn = (w & 1) << 6;
    f32x4 acc[4][4] = {};

    const int lr = l >> 3;
    const int sslot = (l & 7) ^ lr;       // pre-swizzled source slot
    int arow[4], brow[4];
    #pragma unroll
    for (int i = 0; i < 4; i++) {
        int r = (4 * w + i) * 8 + lr;
        arow[i] = min(row0 + r, M - 1);
        brow[i] = col0 + r;
    }
    for (int k0 = 0; k0 < K; k0 += 64) {
        __syncthreads();
        #pragma unroll
        for (int i = 0; i < 4; i++) {
            int ch = 4 * w + i;
            gload_lds16((const void*)(A + (size_t)arow[i] * K + k0 + (sslot << 3)),
                        (void*)(&A_s[ch * 8][0]));
            gload_lds16((const void*)(BT + (size_t)brow[i] * K + k0 + (sslot << 3)),
                        (void*)(&B_s[ch * 8][0]));
        }
        __syncthreads();
        #pragma unroll
        for (int ks = 0; ks < 2; ks++) {
            const int s16 = (ks << 2) + (l >> 4);
            short8 av[4], bv[4];
            #pragma unroll
            for (int i = 0; i < 4; i++) {
                int ar = wm + i * 16 + (l & 15);
                av[i] = *(const short8*)((const char*)&A_s[ar][0] + ((s16 ^ (ar & 7)) << 4));
                int br = wn + i * 16 + (l & 15);
                bv[i] = *(const short8*)((const char*)&B_s[br][0] + ((s16 ^ (br & 7)) << 4));
            }
            #pragma unroll
            for (int i = 0; i < 4; i++)
                #pragma unroll
                for (int j = 0; j < 4; j++)
                    acc[i][j] = __builtin_amdgcn_mfma_f32_16x16x32_bf16(av[i], bv[j], acc[i][j], 0, 0, 0);
        }
    }
    const int rbase = row0 + wm + ((l >> 4) << 2);
    const int cbase = col0 + wn + (l & 15);
    #pragma unroll
    for (int i = 0; i < 4; i++) {
        #pragma unroll
        for (int q = 0; q < 4; q++) {
            int rr = rbase + i * 16 + q;
            if (rr >= M) continue;
            #pragma unroll
            for (int j = 0; j < 4; j++) {
                int c = cbase + j * 16;
                float v = acc[i][j][q] + bias[c];
                if (EPI == 0) {
                    int orow = rr + rr / VNPAT + 1;
                    ((float*)Co)[(size_t)orow * ldc + c] = v;
                } else if (EPI == 1) {
                    ((__hip_bfloat16*)Co)[(size_t)rr * ldc + c] = __float2bfloat16(v);
                } else if (EPI == 2) {
                    ((float*)Co)[(size_t)rr * ldc + c] += v;
                } else {
                    float gl = 0.5f * v * (1.f + erff(v * 0.70710678118654752f));
                    ((__hip_bfloat16*)Co)[(size_t)rr * ldc + c] = __float2bfloat16(gl);
                }
            }
        }
    }
}

// ---------------------------------------------------------------------------
// Attention: one block per (b,h), 512 threads (8 waves). Full K,V staged in
// LDS (bf16). Wave w owns rows r = w, w+8, ... fp32 math.
// qkv layout: [tok][2304] bf16 (q | k | v, each h*64+e). Out: tb [tok][768] bf16.
// ---------------------------------------------------------------------------
__global__ __launch_bounds__(512) void attn2_k(
    const __hip_bfloat16* __restrict__ qkv, __hip_bfloat16* __restrict__ o, float scale)
{
    __shared__ __hip_bfloat16 K_s[VS][66];
    __shared__ __hip_bfloat16 V_s[VS][66];
    __shared__ float p_s[8][200];
    __shared__ float q_s[8][64];
    const int bh = blockIdx.x;
    const int b = bh / VNH, h = bh % VNH;
    const __hip_bfloat16* base = qkv + (size_t)(b * VS) * (3 * VD) + h * VDQ;
    const int tid = threadIdx.x, w = tid >> 6, l = tid & 63;
    for (int idx = tid; idx < VS * VDQ; idx += 512) {
        int t = idx >> 6, d = idx & 63;
        K_s[t][d] = base[(size_t)t * (3 * VD) + VD + d];
        V_s[t][d] = base[(size_t)t * (3 * VD) + 2 * VD + d];
    }
    __syncthreads();
    for (int r = w; r < VS; r += 8) {
        q_s[w][l] = __bfloat162float(base[(size_t)r * (3 * VD) + l]);
        float sv[4];
        #pragma unroll
        for (int i = 0; i < 4; i++) {
            int t = i * 64 + l;
            float a = 0.f;
            if (t < VS) {
                for (int d = 0; d < VDQ; d++)
                    a = fmaf(q_s[w][d], __bfloat162float(K_s[t][d]), a);
                sv[i] = a * scale;
            } else sv[i] = -INFINITY;
        }
        float m = fmaxf(fmaxf(sv[0], sv[1]), fmaxf(sv[2], sv[3]));
        #pragma unroll
        for (int off = 32; off; off >>= 1) m = fmaxf(m, __shfl_xor(m, off));
        float sum = 0.f;
        #pragma unroll
        for (int i = 0; i < 4; i++) { sv[i] = expf(sv[i] - m); sum += sv[i]; }
        #pragma unroll
        for (int off = 32; off; off >>= 1) sum += __shfl_xor(sum, off);
        float inv = 1.f / sum;
        #pragma unroll
        for (int i = 0; i < 4; i++) {
            int t = i * 64 + l;
            if (t < VS) p_s[w][t] = sv[i] * inv;
        }
        float acc = 0.f;
        for (int t = 0; t < VS; t++)
            acc = fmaf(p_s[w][t], __bfloat162float(V_s[t][l]), acc);
        o[((size_t)(b * VS) + r) * VD + h * VDQ + l] = __float2bfloat16(acc);
    }
}

// ---------------------------------------------------------------------------
// fp32 tiled GEMM kept for the tiny head (M=32): C = A @ B + bias
// ---------------------------------------------------------------------------
template<int ACC, int GELU, int ROWMAP>
__global__ __launch_bounds__(256) void gemm_k(
    const float* __restrict__ A, int lda,
    const float* __restrict__ Bw, int ldb,
    const float* __restrict__ bias,
    float* __restrict__ Cm, int ldc,
    int M, int N, int K)
{
    __shared__ float As[16][68];
    __shared__ float Bs[16][68];
    const int tid = threadIdx.x;
    const int tr = tid >> 4, tc = tid & 15;
    const int row0 = blockIdx.y * 64, col0 = blockIdx.x * 64;
    float acc[4][4] = {{0.f}};
    const int nk = K >> 4;
    for (int kt = 0; kt < nk; kt++) {
        const int k0 = kt << 4;
        #pragma unroll
        for (int i = 0; i < 4; i++) {
            int idx = tid + i * 256;
            int r = idx >> 4, c = idx & 15;
            int gr = row0 + r;
            As[c][r] = (gr < M) ? A[(size_t)gr * lda + (k0 + c)] : 0.f;
        }
        #pragma unroll
        for (int i = 0; i < 4; i++) {
            int idx = tid + i * 256;
            int rr = idx >> 6, cc = idx & 63;
            int gc = col0 + cc;
            Bs[rr][cc] = (gc < N) ? Bw[(size_t)(k0 + rr) * ldb + gc] : 0.f;
        }
        __syncthreads();
        #pragma unroll
        for (int kk = 0; kk < 16; kk++) {
            float4 avv = *(const float4*)&As[kk][tr * 4];
            float4 bvv = *(const float4*)&Bs[kk][tc * 4];
            float a4[4] = {avv.x, avv.y, avv.z, avv.w};
            float b4[4] = {bvv.x, bvv.y, bvv.z, bvv.w};
            #pragma unroll
            for (int i = 0; i < 4; i++)
                #pragma unroll
                for (int j = 0; j < 4; j++)
                    acc[i][j] = fmaf(a4[i], b4[j], acc[i][j]);
        }
        __syncthreads();
    }
    #pragma unroll
    for (int i = 0; i < 4; i++) {
        int r = row0 + tr * 4 + i;
        if (r >= M) continue;
        #pragma unroll
        for (int j = 0; j < 4; j++) {
            int c = col0 + tc * 4 + j;
            if (c >= N) continue;
            float v = acc[i][j] + bias[c];
            Cm[(size_t)r * ldc + c] = v;
        }
    }
}

// ---------------------------------------------------------------------------
extern "C" void kernel_launch(void* const* d_in, const int* in_sizes, int n_in,
                              void* d_out, int out_size, void* d_ws, size_t ws_size,
                              hipStream_t stream) {
    (void)in_sizes; (void)n_in; (void)out_size; (void)ws_size;
    const float* X       = (const float*)d_in[0];
    const float* patch_W = (const float*)d_in[1];
    const float* patch_b = (const float*)d_in[2];
    const float* cls_tok = (const float*)d_in[3];
    const float* ln1_g   = (const float*)d_in[4];
    const float* ln1_b   = (const float*)d_in[5];
    const float* Wq      = (const float*)d_in[6];
    const float* bq      = (const float*)d_in[7];
    const float* Wk      = (const float*)d_in[8];
    const float* bk      = (const float*)d_in[9];
    const float* Wv      = (const float*)d_in[10];
    const float* bv      = (const float*)d_in[11];
    const float* proj_W  = (const float*)d_in[12];
    const float* proj_b  = (const float*)d_in[13];
    const float* ln2_g   = (const float*)d_in[14];
    const float* ln2_b   = (const float*)d_in[15];
    const float* mlp_W1  = (const float*)d_in[16];
    const float* mlp_b1  = (const float*)d_in[17];
    const float* mlp_W2  = (const float*)d_in[18];
    const float* mlp_b2  = (const float*)d_in[19];
    const float* head_W  = (const float*)d_in[20];
    const float* head_b  = (const float*)d_in[21];

    char* ws = (char*)d_ws;
    float*          x   = (float*)ws;                             // 19.37 MB fp32
    __hip_bfloat16* tb  = (__hip_bfloat16*)(ws + 19365888);       // 9.68 MB bf16 (LN/attn/etc.)
    __hip_bfloat16* big = (__hip_bfloat16*)(ws + 29048832);       // 38.73 MB (patches/qkv/hidden)
    __hip_bfloat16* wT  = (__hip_bfloat16*)(ws + 67780608);       // 4.72 MB transposed weights
    float*          cb  = (float*)(ws + 72499200);                // 9 KB combined qkv bias

    // patchify -> big
    patchify_k<<<(VB * VNPAT * VP + 255) / 256, 256, 0, stream>>>(X, big);
    // patch_W (256,768) -> wT [768][256]
    {
        dim3 g(VD / 32, VP / 32, 1);
        tpose_k<<<g, 256, 0, stream>>>(patch_W, wT, VP, VD);
    }
    // patch embed GEMM (M=6272,K=256,N=768) with row remap into x
    {
        dim3 g(VD / 128, VB * VNPAT / 128);
        bgemm_k<0><<<g, 256, 0, stream>>>(big, wT, patch_b, x, VB * VNPAT, VP, VD);
    }
    pos_cls_k<<<(unsigned)((TOKD + 255) / 256), 256, 0, stream>>>(x, cls_tok);

    const float scale = 0.125f;
    const size_t WSZ = (size_t)VNH * VD * VDQ;   // 589824 per q/k/v per layer
    for (int l = 0; l < VL; l++) {
        layernorm_k<<<VTOK, 256, 0, stream>>>(x, tb, ln1_g + l * VD, ln1_b + l * VD);

        // q/k/v weight transposes: (12,768,64) -> wT + m*589824 as [h*64+e][d]
        {
            dim3 g(VDQ / 32, VD / 32, VNH);
            tpose_k<<<g, 256, 0, stream>>>(Wq + l * WSZ, wT,               VD, VDQ);
            tpose_k<<<g, 256, 0, stream>>>(Wk + l * WSZ, wT + 1 * VD * VD, VD, VDQ);
            tpose_k<<<g, 256, 0, stream>>>(Wv + l * WSZ, wT + 2 * VD * VD, VD, VDQ);
        }
        cbias_k<<<9, 256, 0, stream>>>(bq + l * VNH * VDQ, bk + l * VNH * VDQ,
                                       bv + l * VNH * VDQ, cb);
        // fused QKV GEMM -> big [tok][2304] bf16
        {
            dim3 g(3 * VD / 128, (VTOK + 127) / 128);
            bgemm_k<1><<<g, 256, 0, stream>>>(tb, wT, cb, big, VTOK, VD, 3 * VD);
        }
        attn2_k<<<VB * VNH, 512, 0, stream>>>(big, tb, scale);

        // proj
        {
            dim3 gt(VD / 32, VD / 32, 1);
            tpose_k<<<gt, 256, 0, stream>>>(proj_W + (size_t)l * VD * VD, wT, VD, VD);
            dim3 g(VD / 128, (VTOK + 127) / 128);
            bgemm_k<2><<<g, 256, 0, stream>>>(tb, wT, proj_b + l * VD, x, VTOK, VD, VD);
        }
        layernorm_k<<<VTOK, 256, 0, stream>>>(x, tb, ln2_g + l * VD, ln2_b + l * VD);
        // MLP1 (gelu -> bf16 hidden in big)
        {
            dim3 gt(VMLP / 32, VD / 32, 1);
            tpose_k<<<gt, 256, 0, stream>>>(mlp_W1 + (size_t)l * VD * VMLP, wT, VD, VMLP);
            dim3 g(VMLP / 128, (VTOK + 127) / 128);
            bgemm_k<3><<<g, 256, 0, stream>>>(tb, wT, mlp_b1 + l * VMLP, big, VTOK, VD, VMLP);
        }
        // MLP2 (accumulate into x)
        {
            dim3 gt(VD / 32, VMLP / 32, 1);
            tpose_k<<<gt, 256, 0, stream>>>(mlp_W2 + (size_t)l * VMLP * VD, wT, VMLP, VD);
            dim3 g(VD / 128, (VTOK + 127) / 128);
            bgemm_k<2><<<g, 256, 0, stream>>>(big, wT, mlp_b2 + l * VD, x, VTOK, VMLP, VD);
        }
    }
    // head: x[:,0] (32,768) @ head_W (768,1000) fp32
    {
        dim3 gh((VC + 63) / 64, 1);
        gemm_k<0, 0, 0><<<gh, 256, 0, stream>>>(x, VS * VD, head_W, VC, head_b,
                                                (float*)d_out, VC, VB, VC, VD);
    }
}

// Round 3
// 3320.429 us; speedup vs baseline: 8.3092x; 1.9459x over previous
//
#include <hip/hip_runtime.h>
#include <hip/hip_bf16.h>
#include <math.h>
#include <stdint.h>

// ViT config
#define VB   32
#define VS   197
#define VD   768
#define VNH  12
#define VDQ  64
#define VL   12
#define VMLP 3072
#define VC   1000
#define VP   256
#define VNPAT 196
#define VTOK (VB * VS)            // 6304
#define TOKD ((size_t)VTOK * VD)  // 4841472 floats

typedef __attribute__((ext_vector_type(4))) float f32x4;
typedef __attribute__((ext_vector_type(8))) short short8;

typedef __attribute__((address_space(1))) const unsigned int GU;
typedef __attribute__((address_space(3))) unsigned int LU;

__device__ __forceinline__ void gload_lds16(const void* g, void* l) {
    __builtin_amdgcn_global_load_lds((GU*)(uintptr_t)g, (LU*)(uintptr_t)l, 16, 0, 0);
}

// ---------------------------------------------------------------------------
// patchify: X (B,224,224) fp32 -> patches (B*196, 256) bf16
// ---------------------------------------------------------------------------
__global__ void patchify_k(const float* __restrict__ X, __hip_bfloat16* __restrict__ P) {
    int idx = blockIdx.x * 256 + threadIdx.x;
    const int total = VB * VNPAT * VP;
    if (idx >= total) return;
    int i  = idx & 255;
    int p  = (idx >> 8) % VNPAT;
    int b  = (idx >> 8) / VNPAT;
    int pr = p / 14, pc = p % 14;
    int a  = i >> 4, c2 = i & 15;
    P[idx] = __float2bfloat16(X[((size_t)b * 224 + pr * 16 + a) * 224 + pc * 16 + c2]);
}

// ---------------------------------------------------------------------------
// cls token + sinusoidal positional embeddings (x fp32)
// ---------------------------------------------------------------------------
__global__ void pos_cls_k(float* __restrict__ x, const float* __restrict__ cls) {
    size_t idx = (size_t)blockIdx.x * 256 + threadIdx.x;
    if (idx >= TOKD) return;
    int j = (int)(idx % VD);
    int s = (int)((idx / VD) % VS);
    float jj = (float)(j & ~1);
    float freq = expf(-(jj / (float)VD) * 9.2103403719761836f);
    float ang  = (float)s * freq;
    float pe   = (j & 1) ? cosf(ang) : sinf(ang);
    if (s == 0) x[idx] = cls[j] + pe;
    else        x[idx] += pe;
}

// ---------------------------------------------------------------------------
// LayerNorm: x fp32 -> y bf16. One block per token.
// ---------------------------------------------------------------------------
__global__ __launch_bounds__(256) void layernorm_k(
    const float* __restrict__ x, __hip_bfloat16* __restrict__ y,
    const float* __restrict__ g, const float* __restrict__ bta)
{
    int t = blockIdx.x;
    const float* xr = x + (size_t)t * VD;
    __hip_bfloat16* yr = y + (size_t)t * VD;
    int tid = threadIdx.x;
    float v[3];
    float s = 0.f;
    #pragma unroll
    for (int i = 0; i < 3; i++) { v[i] = xr[tid + i * 256]; s += v[i]; }
    __shared__ float red[8];
    #pragma unroll
    for (int off = 32; off; off >>= 1) s += __shfl_xor(s, off);
    int lane = tid & 63, w = tid >> 6;
    if (!lane) red[w] = s;
    __syncthreads();
    float mu = (red[0] + red[1] + red[2] + red[3]) * (1.f / VD);
    float s2 = 0.f;
    #pragma unroll
    for (int i = 0; i < 3; i++) { float d0 = v[i] - mu; s2 += d0 * d0; }
    #pragma unroll
    for (int off = 32; off; off >>= 1) s2 += __shfl_xor(s2, off);
    if (!lane) red[4 + w] = s2;
    __syncthreads();
    float var = (red[4] + red[5] + red[6] + red[7]) * (1.f / VD);
    float rs = rsqrtf(var + 1e-5f);
    #pragma unroll
    for (int i = 0; i < 3; i++) {
        int j = tid + i * 256;
        yr[j] = __float2bfloat16((v[i] - mu) * rs * g[j] + bta[j]);
    }
}

// ---------------------------------------------------------------------------
// Batched transpose + bf16 convert: in (G,R,C) fp32 -> out (G,C,R) bf16.
// ---------------------------------------------------------------------------
__global__ __launch_bounds__(256) void tpose_k(
    const float* __restrict__ in, __hip_bfloat16* __restrict__ out, int R, int C)
{
    __shared__ float t[32][33];
    const float* ing = in + (size_t)blockIdx.z * R * C;
    __hip_bfloat16* outg = out + (size_t)blockIdx.z * R * C;
    int c0 = blockIdx.x * 32, r0 = blockIdx.y * 32;
    int tc = threadIdx.x & 31, tr = threadIdx.x >> 5;
    #pragma unroll
    for (int p = 0; p < 4; p++)
        t[tr + p * 8][tc] = ing[(size_t)(r0 + tr + p * 8) * C + c0 + tc];
    __syncthreads();
    #pragma unroll
    for (int p = 0; p < 4; p++)
        outg[(size_t)(c0 + tr + p * 8) * R + r0 + tc] = __float2bfloat16(t[tc][tr + p * 8]);
}

// combined qkv bias
__global__ void cbias_k(const float* __restrict__ bq, const float* __restrict__ bk,
                        const float* __restrict__ bv, float* __restrict__ cb) {
    int n = blockIdx.x * 256 + threadIdx.x;
    if (n >= 3 * VD) return;
    int m = n / VD, wi = n % VD;
    const float* p = (m == 0) ? bq : (m == 1) ? bk : bv;
    cb[n] = p[wi];
}

// ---------------------------------------------------------------------------
// bf16 MFMA GEMM (m97-style 128x128, BK=64) — unchanged from round 2
// ---------------------------------------------------------------------------
template<int EPI>
__global__ __launch_bounds__(256) void bgemm_k(
    const __hip_bfloat16* __restrict__ A,
    const __hip_bfloat16* __restrict__ BT,
    const float* __restrict__ bias,
    void* __restrict__ Co,
    int M, int K, int ldc)
{
    __shared__ short A_s[128][64];
    __shared__ short B_s[128][64];
    const int tid = threadIdx.x;
    const int w = tid >> 6, l = tid & 63;
    const int row0 = blockIdx.y * 128, col0 = blockIdx.x * 128;
    const int wm = (w >> 1) << 6, wn = (w & 1) << 6;
    f32x4 acc[4][4] = {};

    const int lr = l >> 3;
    const int sslot = (l & 7) ^ lr;
    int arow[4], brow[4];
    #pragma unroll
    for (int i = 0; i < 4; i++) {
        int r = (4 * w + i) * 8 + lr;
        arow[i] = min(row0 + r, M - 1);
        brow[i] = col0 + r;
    }
    for (int k0 = 0; k0 < K; k0 += 64) {
        __syncthreads();
        #pragma unroll
        for (int i = 0; i < 4; i++) {
            int ch = 4 * w + i;
            gload_lds16((const void*)(A + (size_t)arow[i] * K + k0 + (sslot << 3)),
                        (void*)(&A_s[ch * 8][0]));
            gload_lds16((const void*)(BT + (size_t)brow[i] * K + k0 + (sslot << 3)),
                        (void*)(&B_s[ch * 8][0]));
        }
        __syncthreads();
        #pragma unroll
        for (int ks = 0; ks < 2; ks++) {
            const int s16 = (ks << 2) + (l >> 4);
            short8 av[4], bv[4];
            #pragma unroll
            for (int i = 0; i < 4; i++) {
                int ar = wm + i * 16 + (l & 15);
                av[i] = *(const short8*)((const char*)&A_s[ar][0] + ((s16 ^ (ar & 7)) << 4));
                int br = wn + i * 16 + (l & 15);
                bv[i] = *(const short8*)((const char*)&B_s[br][0] + ((s16 ^ (br & 7)) << 4));
            }
            #pragma unroll
            for (int i = 0; i < 4; i++)
                #pragma unroll
                for (int j = 0; j < 4; j++)
                    acc[i][j] = __builtin_amdgcn_mfma_f32_16x16x32_bf16(av[i], bv[j], acc[i][j], 0, 0, 0);
        }
    }
    const int rbase = row0 + wm + ((l >> 4) << 2);
    const int cbase = col0 + wn + (l & 15);
    #pragma unroll
    for (int i = 0; i < 4; i++) {
        #pragma unroll
        for (int q = 0; q < 4; q++) {
            int rr = rbase + i * 16 + q;
            if (rr >= M) continue;
            #pragma unroll
            for (int j = 0; j < 4; j++) {
                int c = cbase + j * 16;
                float v = acc[i][j][q] + bias[c];
                if (EPI == 0) {
                    int orow = rr + rr / VNPAT + 1;
                    ((float*)Co)[(size_t)orow * ldc + c] = v;
                } else if (EPI == 1) {
                    ((__hip_bfloat16*)Co)[(size_t)rr * ldc + c] = __float2bfloat16(v);
                } else if (EPI == 2) {
                    ((float*)Co)[(size_t)rr * ldc + c] += v;
                } else {
                    float gl = 0.5f * v * (1.f + erff(v * 0.70710678118654752f));
                    ((__hip_bfloat16*)Co)[(size_t)rr * ldc + c] = __float2bfloat16(gl);
                }
            }
        }
    }
}

// ---------------------------------------------------------------------------
// MFMA attention. One block per (b,h), 256 threads (4 waves), 64 KB LDS.
// Wave w handles q-tiles {w, w+4, w+8, (w==0: 12)} of 13 (16 rows each).
// Phase 1: S^T tile = mfma(K_frag, Q_frag): lane holds scores for q=lane&15,
//          k = 16t + 4*(lane>>4) + reg  -> in-lane softmax + shfl_xor(16,32).
// Phase 2: P (bf16, inv folded) -> swizzled LDS; O = mfma(P_frag, V_frag)
//          with V^T staged swizzled in LDS, contraction padded to 224.
// Q/K fragments are read from global (L2-resident per-head tiles).
// ---------------------------------------------------------------------------
__device__ __forceinline__ int swz_idx(int row, int k) {
    // row*256 shorts (512B rows), 16B slots XOR-swizzled by row&7
    return row * 256 + (((k >> 3) ^ (row & 7)) << 3) + (k & 7);
}
__device__ __forceinline__ unsigned pack_bf16(float a, float b) {
    __hip_bfloat16 x = __float2bfloat16(a), y = __float2bfloat16(b);
    unsigned short ux = *(unsigned short*)&x, uy = *(unsigned short*)&y;
    return (unsigned)ux | ((unsigned)uy << 16);
}

__global__ __launch_bounds__(256) void attn3_k(
    const __hip_bfloat16* __restrict__ qkv, __hip_bfloat16* __restrict__ o)
{
    __shared__ short V_t[64 * 256];      // 32 KB: V^T, rows = e (64), k padded to 224
    __shared__ short P_s[4][16 * 256];   // 32 KB: per-wave P, rows = q_local
    const int bh = blockIdx.x;
    const int b = bh / VNH, h = bh % VNH;
    const int tid = threadIdx.x, w = tid >> 6, l = tid & 63;
    const int g = l >> 4, c16 = l & 15;

    const __hip_bfloat16* base = qkv + (size_t)(b * VS) * (3 * VD) + h * VDQ;

    // ---- stage V^T (swizzled) ----
    {
        const __hip_bfloat16* vbase = base + 2 * VD;
        int t = tid & 31, e0 = (tid >> 5) * 8;
        #pragma unroll
        for (int it = 0; it < 7; it++) {
            int tt = it * 32 + t;
            if (tt < VS) {
                short8 vv = *(const short8*)(vbase + (size_t)tt * (3 * VD) + e0);
                #pragma unroll
                for (int j = 0; j < 8; j++) V_t[swz_idx(e0 + j, tt)] = vv[j];
            }
        }
        for (int idx = tid; idx < 64 * 27; idx += 256) {
            int e = idx / 27, k = 197 + idx % 27;
            V_t[swz_idx(e, k)] = 0;
        }
    }
    // zero P pad (k = 208..223) for this wave's rows
    {
        unsigned* p0 = (unsigned*)&P_s[w][swz_idx(c16, 208 + g * 4)];
        p0[0] = 0; p0[1] = 0;
    }
    __syncthreads();

    for (int qt = w; qt < 13; qt += 4) {
        const int q0 = qt * 16;
        // Q fragment (B-operand): col q = q0 + c16, 8 contiguous d at 32*ks + 8*g
        int qr = min(q0 + c16, VS - 1);
        const __hip_bfloat16* qp = base + (size_t)qr * (3 * VD) + g * 8;
        short8 qa0 = *(const short8*)(qp);
        short8 qa1 = *(const short8*)(qp + 32);

        f32x4 st[13];
        #pragma unroll
        for (int t = 0; t < 13; t++) {
            int kr = min(t * 16 + c16, VS - 1);
            const __hip_bfloat16* kp = base + VD + (size_t)kr * (3 * VD) + g * 8;
            short8 ka0 = *(const short8*)(kp);
            short8 ka1 = *(const short8*)(kp + 32);
            f32x4 z = {};
            z = __builtin_amdgcn_mfma_f32_16x16x32_bf16(ka0, qa0, z, 0, 0, 0);
            z = __builtin_amdgcn_mfma_f32_16x16x32_bf16(ka1, qa1, z, 0, 0, 0);
            st[t] = z;
        }
        // scale + mask (k = 16t + 4g + reg >= 197 only possible at t=12)
        #pragma unroll
        for (int t = 0; t < 13; t++) {
            #pragma unroll
            for (int r = 0; r < 4; r++) {
                float v = st[t][r] * 0.125f;
                if (t == 12 && (4 * g + r) >= 5) v = -3.0e38f;
                st[t][r] = v;
            }
        }
        // softmax over the 52 in-lane scores (row q = c16)
        float m = -3.0e38f;
        #pragma unroll
        for (int t = 0; t < 13; t++)
            #pragma unroll
            for (int r = 0; r < 4; r++) m = fmaxf(m, st[t][r]);
        m = fmaxf(m, __shfl_xor(m, 16));
        m = fmaxf(m, __shfl_xor(m, 32));
        float sum = 0.f;
        #pragma unroll
        for (int t = 0; t < 13; t++)
            #pragma unroll
            for (int r = 0; r < 4; r++) { float e = expf(st[t][r] - m); st[t][r] = e; sum += e; }
        sum += __shfl_xor(sum, 16);
        sum += __shfl_xor(sum, 32);
        float inv = 1.f / sum;
        // write P (bf16, inv folded): row q=c16, k = 16t + 4g + {0..3}
        #pragma unroll
        for (int t = 0; t < 13; t++) {
            int k0 = 16 * t + 4 * g;
            unsigned* pp = (unsigned*)&P_s[w][swz_idx(c16, k0)];
            pp[0] = pack_bf16(st[t][0] * inv, st[t][1] * inv);
            pp[1] = pack_bf16(st[t][2] * inv, st[t][3] * inv);
        }
        // PV: O[q][e] += P[q][k] * V[k][e], contraction 224 = 7 x 32
        f32x4 acc[4] = {};
        #pragma unroll
        for (int ki = 0; ki < 7; ki++) {
            int k0 = ki * 32 + g * 8;
            short8 pa = *(const short8*)&P_s[w][swz_idx(c16, k0)];
            #pragma unroll
            for (int et = 0; et < 4; et++) {
                short8 vbf = *(const short8*)&V_t[swz_idx(et * 16 + c16, k0)];
                acc[et] = __builtin_amdgcn_mfma_f32_16x16x32_bf16(pa, vbf, acc[et], 0, 0, 0);
            }
        }
        // store O: row q = q0 + 4g + reg, col e = et*16 + c16
        #pragma unroll
        for (int et = 0; et < 4; et++) {
            #pragma unroll
            for (int r = 0; r < 4; r++) {
                int q = q0 + 4 * g + r;
                if (q < VS)
                    o[((size_t)(b * VS) + q) * VD + h * VDQ + et * 16 + c16] =
                        __float2bfloat16(acc[et][r]);
            }
        }
    }
}

// ---------------------------------------------------------------------------
// fp32 tiled GEMM kept for the tiny head (M=32)
// ---------------------------------------------------------------------------
template<int ACC, int GELU, int ROWMAP>
__global__ __launch_bounds__(256) void gemm_k(
    const float* __restrict__ A, int lda,
    const float* __restrict__ Bw, int ldb,
    const float* __restrict__ bias,
    float* __restrict__ Cm, int ldc,
    int M, int N, int K)
{
    __shared__ float As[16][68];
    __shared__ float Bs[16][68];
    const int tid = threadIdx.x;
    const int tr = tid >> 4, tc = tid & 15;
    const int row0 = blockIdx.y * 64, col0 = blockIdx.x * 64;
    float acc[4][4] = {{0.f}};
    const int nk = K >> 4;
    for (int kt = 0; kt < nk; kt++) {
        const int k0 = kt << 4;
        #pragma unroll
        for (int i = 0; i < 4; i++) {
            int idx = tid + i * 256;
            int r = idx >> 4, c = idx & 15;
            int gr = row0 + r;
            As[c][r] = (gr < M) ? A[(size_t)gr * lda + (k0 + c)] : 0.f;
        }
        #pragma unroll
        for (int i = 0; i < 4; i++) {
            int idx = tid + i * 256;
            int rr = idx >> 6, cc = idx & 63;
            int gc = col0 + cc;
            Bs[rr][cc] = (gc < N) ? Bw[(size_t)(k0 + rr) * ldb + gc] : 0.f;
        }
        __syncthreads();
        #pragma unroll
        for (int kk = 0; kk < 16; kk++) {
            float4 avv = *(const float4*)&As[kk][tr * 4];
            float4 bvv = *(const float4*)&Bs[kk][tc * 4];
            float a4[4] = {avv.x, avv.y, avv.z, avv.w};
            float b4[4] = {bvv.x, bvv.y, bvv.z, bvv.w};
            #pragma unroll
            for (int i = 0; i < 4; i++)
                #pragma unroll
                for (int j = 0; j < 4; j++)
                    acc[i][j] = fmaf(a4[i], b4[j], acc[i][j]);
        }
        __syncthreads();
    }
    #pragma unroll
    for (int i = 0; i < 4; i++) {
        int r = row0 + tr * 4 + i;
        if (r >= M) continue;
        #pragma unroll
        for (int j = 0; j < 4; j++) {
            int c = col0 + tc * 4 + j;
            if (c >= N) continue;
            Cm[(size_t)r * ldc + c] = acc[i][j] + bias[c];
        }
    }
}

// ---------------------------------------------------------------------------
extern "C" void kernel_launch(void* const* d_in, const int* in_sizes, int n_in,
                              void* d_out, int out_size, void* d_ws, size_t ws_size,
                              hipStream_t stream) {
    (void)in_sizes; (void)n_in; (void)out_size; (void)ws_size;
    const float* X       = (const float*)d_in[0];
    const float* patch_W = (const float*)d_in[1];
    const float* patch_b = (const float*)d_in[2];
    const float* cls_tok = (const float*)d_in[3];
    const float* ln1_g   = (const float*)d_in[4];
    const float* ln1_b   = (const float*)d_in[5];
    const float* Wq      = (const float*)d_in[6];
    const float* bq      = (const float*)d_in[7];
    const float* Wk      = (const float*)d_in[8];
    const float* bk      = (const float*)d_in[9];
    const float* Wv      = (const float*)d_in[10];
    const float* bv      = (const float*)d_in[11];
    const float* proj_W  = (const float*)d_in[12];
    const float* proj_b  = (const float*)d_in[13];
    const float* ln2_g   = (const float*)d_in[14];
    const float* ln2_b   = (const float*)d_in[15];
    const float* mlp_W1  = (const float*)d_in[16];
    const float* mlp_b1  = (const float*)d_in[17];
    const float* mlp_W2  = (const float*)d_in[18];
    const float* mlp_b2  = (const float*)d_in[19];
    const float* head_W  = (const float*)d_in[20];
    const float* head_b  = (const float*)d_in[21];

    char* ws = (char*)d_ws;
    float*          x   = (float*)ws;                             // 19.37 MB fp32
    __hip_bfloat16* tb  = (__hip_bfloat16*)(ws + 19365888);       // 9.68 MB bf16
    __hip_bfloat16* big = (__hip_bfloat16*)(ws + 29048832);       // 38.73 MB (patches/qkv/hidden)
    __hip_bfloat16* wT  = (__hip_bfloat16*)(ws + 67780608);       // 4.72 MB transposed weights
    float*          cb  = (float*)(ws + 72499200);                // 9 KB combined qkv bias

    patchify_k<<<(VB * VNPAT * VP + 255) / 256, 256, 0, stream>>>(X, big);
    {
        dim3 g(VD / 32, VP / 32, 1);
        tpose_k<<<g, 256, 0, stream>>>(patch_W, wT, VP, VD);
    }
    {
        dim3 g(VD / 128, VB * VNPAT / 128);
        bgemm_k<0><<<g, 256, 0, stream>>>(big, wT, patch_b, x, VB * VNPAT, VP, VD);
    }
    pos_cls_k<<<(unsigned)((TOKD + 255) / 256), 256, 0, stream>>>(x, cls_tok);

    const size_t WSZ = (size_t)VNH * VD * VDQ;
    for (int l = 0; l < VL; l++) {
        layernorm_k<<<VTOK, 256, 0, stream>>>(x, tb, ln1_g + l * VD, ln1_b + l * VD);

        {
            dim3 g(VDQ / 32, VD / 32, VNH);
            tpose_k<<<g, 256, 0, stream>>>(Wq + l * WSZ, wT,               VD, VDQ);
            tpose_k<<<g, 256, 0, stream>>>(Wk + l * WSZ, wT + 1 * VD * VD, VD, VDQ);
            tpose_k<<<g, 256, 0, stream>>>(Wv + l * WSZ, wT + 2 * VD * VD, VD, VDQ);
        }
        cbias_k<<<9, 256, 0, stream>>>(bq + l * VNH * VDQ, bk + l * VNH * VDQ,
                                       bv + l * VNH * VDQ, cb);
        {
            dim3 g(3 * VD / 128, (VTOK + 127) / 128);
            bgemm_k<1><<<g, 256, 0, stream>>>(tb, wT, cb, big, VTOK, VD, 3 * VD);
        }
        attn3_k<<<VB * VNH, 256, 0, stream>>>(big, tb);

        {
            dim3 gt(VD / 32, VD / 32, 1);
            tpose_k<<<gt, 256, 0, stream>>>(proj_W + (size_t)l * VD * VD, wT, VD, VD);
            dim3 g(VD / 128, (VTOK + 127) / 128);
            bgemm_k<2><<<g, 256, 0, stream>>>(tb, wT, proj_b + l * VD, x, VTOK, VD, VD);
        }
        layernorm_k<<<VTOK, 256, 0, stream>>>(x, tb, ln2_g + l * VD, ln2_b + l * VD);
        {
            dim3 gt(VMLP / 32, VD / 32, 1);
            tpose_k<<<gt, 256, 0, stream>>>(mlp_W1 + (size_t)l * VD * VMLP, wT, VD, VMLP);
            dim3 g(VMLP / 128, (VTOK + 127) / 128);
            bgemm_k<3><<<g, 256, 0, stream>>>(tb, wT, mlp_b1 + l * VMLP, big, VTOK, VD, VMLP);
        }
        {
            dim3 gt(VD / 32, VMLP / 32, 1);
            tpose_k<<<gt, 256, 0, stream>>>(mlp_W2 + (size_t)l * VMLP * VD, wT, VMLP, VD);
            dim3 g(VD / 128, (VTOK + 127) / 128);
            bgemm_k<2><<<g, 256, 0, stream>>>(big, wT, mlp_b2 + l * VD, x, VTOK, VMLP, VD);
        }
    }
    {
        dim3 gh((VC + 63) / 64, 1);
        gemm_k<0, 0, 0><<<gh, 256, 0, stream>>>(x, VS * VD, head_W, VC, head_b,
                                                (float*)d_out, VC, VB, VC, VD);
    }
}